// Round 25
// baseline (172.811 us; speedup 1.0000x reference)
//
#include <hip/hip_runtime.h>
#include <cstdint>
#include <cstddef>

typedef __attribute__((ext_vector_type(8))) short bfrag;      // 8x16-bit (4 VGPR)
typedef __attribute__((ext_vector_type(8))) _Float16 hfrag;   // 8 f16 (4 VGPR)
typedef __attribute__((ext_vector_type(2))) __fp16 fp16x2;    // cvt_pkrtz result type
typedef __attribute__((ext_vector_type(4))) float f4;         // 16x16 MFMA C/D
typedef __attribute__((ext_vector_type(16))) float f16v;      // 32x32 MFMA C/D
typedef __attribute__((ext_vector_type(4))) unsigned short us4;

#define MFMA16H(a, b, c) __builtin_amdgcn_mfma_f32_16x16x32_f16(a, b, c, 0, 0, 0)
#define MFMA32H(a, b, c) __builtin_amdgcn_mfma_f32_32x32x16_f16(a, b, c, 0, 0, 0)

// ---------------------------------------------------------------------------
// fp16 / math helpers.
// ---------------------------------------------------------------------------
__device__ __forceinline__ unsigned cvt_pkrtz_u(float a, float b) {
  union { fp16x2 h; unsigned u; } c;
  c.h = __builtin_amdgcn_cvt_pkrtz(a, b);
  return c.u;
}
__device__ __forceinline__ unsigned short f2h_bits(float x) {  // RNE
  _Float16 h = (_Float16)x;
  union { _Float16 h; unsigned short u; } c;
  c.h = h;
  return c.u;
}
__device__ __forceinline__ float h2f(unsigned short u) {
  union { unsigned short u; _Float16 h; } c;
  c.u = u;
  return (float)c.h;
}
// One-instruction cross-half exchange: a' = [a_lo | b_lo], b' = [a_hi | b_hi].
__device__ __forceinline__ void permswap(unsigned& a, unsigned& b) {
  auto r = __builtin_amdgcn_permlane32_swap((int)a, (int)b, false, false);
  a = (unsigned)r[0];
  b = (unsigned)r[1];
}
// Async global->LDS, 16B per lane. Dest is wave-uniform base + lane*16.
__device__ __forceinline__ void gl16(const unsigned short* g, unsigned short* l) {
  __builtin_amdgcn_global_load_lds(
      (const __attribute__((address_space(1))) unsigned int*)g,
      (__attribute__((address_space(3))) unsigned int*)l, 16, 0, 0);
}
// 3-input max (single instruction, T17).
__device__ __forceinline__ float max3f(float a, float b, float c) {
  float r;
  asm("v_max3_f32 %0, %1, %2, %3" : "=v"(r) : "v"(a), "v"(b), "v"(c));
  return r;
}
// Raw v_exp_f32 (computes 2^x).
__device__ __forceinline__ float exp2_fast(float x) {
  float r;
  asm("v_exp_f32 %0, %1" : "=v"(r) : "v"(x));
  return r;
}

// ---------------------------------------------------------------------------
// Software-exact OCP e4m3fn rounding (RTNE via magic-add; matches ml_dtypes
// bit-exact incl. subnormal grid 2^-9 and the 448-saturation region).
// ---------------------------------------------------------------------------
__device__ __forceinline__ float qd_e4m3(float v) {
  float a = fabsf(v);
  unsigned u = __float_as_uint(a);
  int e = (int)(u >> 23) - 127;
  int k = e - 3;
  if (k < -9) k = -9;
  float big = __uint_as_float((unsigned)(k + 150) << 23);  // 2^(k+23)
  float r = (a + big) - big;
  return __builtin_copysignf(r, v);
}

// ---------------------------------------------------------------------------
// Activation quant (fp32 input): per 128-block, e4m3 codes as fp16 + scale.
// ---------------------------------------------------------------------------
__global__ __launch_bounds__(256) void quant_x(const float* __restrict__ src,
                                               unsigned short* __restrict__ q,
                                               float* __restrict__ s,
                                               int nblk) {
  int gid = blockIdx.x * 256 + threadIdx.x;
  int wid = gid >> 6;
  int lane = gid & 63;
  if (wid >= nblk) return;
  size_t off = (size_t)wid * 128 + lane * 2;
  float2 xv = *reinterpret_cast<const float2*>(src + off);
  float m = fmaxf(fabsf(xv.x), fabsf(xv.y));
#pragma unroll
  for (int d = 32; d > 0; d >>= 1) m = fmaxf(m, __shfl_xor(m, d));
  float scale = fmaxf(m / 448.0f, 1e-12f);
  unsigned short q0 = f2h_bits(qd_e4m3(xv.x / scale));  // exact: e4m3 ⊂ fp16
  unsigned short q1 = f2h_bits(qd_e4m3(xv.y / scale));
  *reinterpret_cast<unsigned*>(q + off) = (unsigned)q0 | ((unsigned)q1 << 16);
  if (lane == 0) s[wid] = scale;
}

// ---------------------------------------------------------------------------
// Activation quant (fp16 input): same math, reads half the bytes.
// ---------------------------------------------------------------------------
__global__ __launch_bounds__(256) void quant_xh(const unsigned short* __restrict__ src,
                                                unsigned short* __restrict__ q,
                                                float* __restrict__ s,
                                                int nblk) {
  int gid = blockIdx.x * 256 + threadIdx.x;
  int wid = gid >> 6;
  int lane = gid & 63;
  if (wid >= nblk) return;
  size_t off = (size_t)wid * 128 + lane * 2;
  unsigned hv = *reinterpret_cast<const unsigned*>(src + off);
  float x0 = h2f((unsigned short)(hv & 0xffffu));
  float x1 = h2f((unsigned short)(hv >> 16));
  float m = fmaxf(fabsf(x0), fabsf(x1));
#pragma unroll
  for (int d = 32; d > 0; d >>= 1) m = fmaxf(m, __shfl_xor(m, d));
  float scale = fmaxf(m / 448.0f, 1e-12f);
  unsigned short q0 = f2h_bits(qd_e4m3(x0 / scale));
  unsigned short q1 = f2h_bits(qd_e4m3(x1 / scale));
  *reinterpret_cast<unsigned*>(q + off) = (unsigned)q0 | ((unsigned)q1 << 16);
  if (lane == 0) s[wid] = scale;
}

// ---------------------------------------------------------------------------
// Weight quant + dequant -> FP16 (RNE, rel err <= 2^-12) + TRANSPOSE.
// ---------------------------------------------------------------------------
__global__ __launch_bounds__(256) void quant_w_t(const float* __restrict__ W,
                                                 unsigned short* __restrict__ WT,
                                                 int K, int N) {
  __shared__ __align__(16) unsigned short Ht[128][72];
  const int tid = threadIdx.x;
  const int w = tid >> 6, l = tid & 63;
  const int k0 = blockIdx.y * 64, n0 = blockIdx.x * 128;
#pragma unroll 4
  for (int i = 0; i < 16; ++i) {
    int kl = w * 16 + i;
    float2 xv = *reinterpret_cast<const float2*>(&W[(size_t)(k0 + kl) * N + n0 + l * 2]);
    float m = fmaxf(fabsf(xv.x), fabsf(xv.y));
#pragma unroll
    for (int d = 32; d > 0; d >>= 1) m = fmaxf(m, __shfl_xor(m, d));
    float scale = fmaxf(m / 448.0f, 1e-12f);
    Ht[l * 2][kl]     = f2h_bits(qd_e4m3(xv.x / scale) * scale);
    Ht[l * 2 + 1][kl] = f2h_bits(qd_e4m3(xv.y / scale) * scale);
  }
  __syncthreads();
  const int n = tid & 127, hs = tid >> 7;   // thread -> (n-row, k-half)
  unsigned short* dst = WT + (size_t)(n0 + n) * K + k0 + hs * 32;
#pragma unroll
  for (int j = 0; j < 4; ++j)
    *reinterpret_cast<bfrag*>(dst + j * 8) =
        *reinterpret_cast<const bfrag*>(&Ht[n][hs * 32 + j * 8]);
}

// ---------------------------------------------------------------------------
// Quantization-aware MFMA GEMM, FP16 1-PASS (round-20 version, unchanged).
// ---------------------------------------------------------------------------
template <int MF, bool SPLIT>
__global__ __launch_bounds__(256, 2) void gemm_q(const unsigned short* __restrict__ Aq,
                                                 const float* __restrict__ As,
                                                 const unsigned short* __restrict__ WT,
                                                 const float* __restrict__ bias,
                                                 float* __restrict__ Cf,
                                                 unsigned short* __restrict__ C16,
                                                 int M, int N, int K) {
  constexpr int MT = MF * 32;
  __shared__ __align__(16) unsigned short Al[MT][64];
  __shared__ __align__(16) unsigned short Bh[128][64];
  __shared__ float Ss[MT][8];
  const int tid = threadIdx.x;
  const int w = tid >> 6, l = tid & 63;
  const int lr = l & 15, lg = l >> 4;
  const int nbx = N >> 7;
  const int nwg = nbx * (M / MT);
  const int q8 = nwg >> 3;
  const int swz = ((int)blockIdx.x & 7) * q8 + ((int)blockIdx.x >> 3);
  const int row0 = (swz / nbx) * MT, col0 = (swz % nbx) << 7;
  const int wr = (w >> 1) * (MT / 2), wc = (w & 1) * 64;
  const int xsw = (lr & 7) * 8;        // read-side XOR (short units)

  if (MF == 4) {
    int r = tid >> 1, c0 = (tid & 1) * 4;
    *reinterpret_cast<float4*>(&Ss[r][c0]) =
        *reinterpret_cast<const float4*>(&As[(size_t)(row0 + r) * 8 + c0]);
  } else {
    int r = tid >> 2, c0 = (tid & 3) * 2;
    *reinterpret_cast<float2*>(&Ss[r][c0]) =
        *reinterpret_cast<const float2*>(&As[(size_t)(row0 + r) * 8 + c0]);
  }

  f4 acc[MF][4], seg[MF][4];
#pragma unroll
  for (int i = 0; i < MF; ++i)
#pragma unroll
    for (int j = 0; j < 4; ++j)
#pragma unroll
      for (int c = 0; c < 4; ++c) {
        acc[i][j][c] = 0.f;
        seg[i][j][c] = 0.f;
      }

  const int lrow = l >> 3;             // 0..7
  const int jch = (l & 7) ^ lrow;      // inverse-swizzled source chunk
  const unsigned short* pA = Aq + (size_t)(row0 + w * (MT / 4) + lrow) * K + jch * 8;
  const unsigned short* pH = WT + (size_t)(col0 + w * 32 + lrow) * K + jch * 8;
  unsigned short* dA = &Al[0][0] + w * (MT / 4) * 64;
  unsigned short* dH = &Bh[0][0] + w * 2048;

  const int niter = K >> 6;
  for (int it = 0; it < niter; ++it) {
    const int k0 = it << 6;
    __syncthreads();
#pragma unroll
    for (int ii = 0; ii < MF; ++ii)
      gl16(pA + (size_t)ii * 8 * K + k0, dA + ii * 512);
#pragma unroll
    for (int ii = 0; ii < 4; ++ii)
      gl16(pH + (size_t)ii * 8 * K + k0, dH + ii * 512);
    __syncthreads();

#pragma unroll
    for (int ks = 0; ks < 2; ++ks) {
      hfrag af[MF];
#pragma unroll
      for (int mf = 0; mf < MF; ++mf)
        af[mf] = *reinterpret_cast<const hfrag*>(
            &Al[0][0] + (wr + mf * 16 + lr) * 64 + ((ks * 32 + lg * 8) ^ xsw));
#pragma unroll
      for (int nf = 0; nf < 4; ++nf) {
        hfrag bh = *reinterpret_cast<const hfrag*>(
            &Bh[0][0] + (wc + nf * 16 + lr) * 64 + ((ks * 32 + lg * 8) ^ xsw));
#pragma unroll
        for (int mf = 0; mf < MF; ++mf)
          seg[mf][nf] = MFMA16H(af[mf], bh, seg[mf][nf]);
      }
    }

    if (it & 1) {
      const int kb = it >> 1;
#pragma unroll
      for (int mf = 0; mf < MF; ++mf) {
        float sv[4];
#pragma unroll
        for (int r = 0; r < 4; ++r) sv[r] = Ss[wr + mf * 16 + lg * 4 + r][kb];
#pragma unroll
        for (int nf = 0; nf < 4; ++nf)
#pragma unroll
          for (int r = 0; r < 4; ++r) {
            acc[mf][nf][r] += sv[r] * seg[mf][nf][r];
            seg[mf][nf][r] = 0.f;
          }
      }
    }
  }

#pragma unroll
  for (int mf = 0; mf < MF; ++mf) {
#pragma unroll
    for (int r = 0; r < 4; ++r) {
      const int m = row0 + wr + mf * 16 + lg * 4 + r;
#pragma unroll
      for (int nf = 0; nf < 4; ++nf) {
        const int col = col0 + wc + nf * 16 + lr;
        float o = acc[mf][nf][r] + bias[col];
        if (SPLIT) {
          C16[(size_t)m * N + col] = f2h_bits(o);  // single fp16 stream
        } else {
          Cf[(size_t)m * N + col] = o;
        }
      }
    }
  }
}

// ---------------------------------------------------------------------------
// Single-stream fp16 1-pass flash attention, KBLK=64 (round 25): each
// iteration covers 64 k-positions in two 32-k sub-tiles (S pairs), halving
// the per-iteration fixed costs: barriers 64->32, defer-max checks+rescale,
// cross-lane shuffles, K-pointer bookkeeping. V LDS pitch 68 shorts
// (34 dwords, gcd 2 -> 2-way banks = free). fp16 output epilogue (r24).
// ---------------------------------------------------------------------------
__global__ __launch_bounds__(256, 2) void attn_mfma32(const unsigned short* __restrict__ qkv,
                                                      unsigned short* __restrict__ out16) {
  __shared__ __align__(16) unsigned short Vth[2][64][68];  // V^T: [buf][rho(d)][kpos 0..63]
  const int tid = threadIdx.x;
  const int w = tid >> 6, l = tid & 63;
  const int q = l & 31;
  const int hi = l >> 5;
  // XCD-aware decode: XCD k owns bh in {4k..4k+3} (2 MB KV -> L2-resident)
  const int lin = (int)blockIdx.x;
  const int xcd = lin & 7, j = lin >> 3;
  const int bh = 4 * xcd + (j >> 4);
  const int qt = j & 15;
  const int q0 = qt * 128 + w * 32;
  const int b = bh >> 4, h = bh & 15;
  const size_t bbase = (size_t)b * 2048;
  const size_t hoff = (size_t)h * 64;
  const float C = 0.18033688011112042f;  // 0.125 * log2(e)

  const int rA = (q & 24) | ((q + (q >> 3)) & 7);              // d = q
  const int rB = 32 + ((q & 24) | ((q + 4 + (q >> 3)) & 7));   // d = 32+q

  hfrag qh[4];
  {
    const size_t qrow = (bbase + q0 + q) * 3072 + hoff + hi * 8;
#pragma unroll
    for (int f = 0; f < 4; ++f)
      qh[f] = *reinterpret_cast<const hfrag*>(qkv + qrow + f * 16);
  }

  const int skp = tid >> 3;   // 0..31 (kpos within sub-tile)
  const int sc = tid & 7;     // 0..7  (d-chunk of 8)

  const size_t SUB = (size_t)32 * 3072;      // 32 rows
  const size_t KSTEP = (size_t)64 * 3072;    // one 64-k tile
  const unsigned short* kph = qkv + (bbase + q) * 3072 + 1024 + hoff + hi * 8;
  const unsigned short* vph = qkv + (bbase + skp) * 3072 + 2048 + hoff + sc * 8;

  hfrag kh0[4], kh1[4];
  bfrag svh0, svh1;

#define VSTAGE(BUF)                                                            \
  do {                                                                         \
    _Pragma("unroll") for (int j2 = 0; j2 < 8; ++j2) {                         \
      int row = sc * 8 + ((j2 + sc) & 7);                                      \
      Vth[BUF][row][skp] = (unsigned short)svh0[j2];                           \
      Vth[BUF][row][32 + skp] = (unsigned short)svh1[j2];                      \
    }                                                                          \
  } while (0)

  // ---- prologue: K(0), V(0)->LDS0, QK(0)->sA pair, K(1) ----
#pragma unroll
  for (int f = 0; f < 4; ++f) {
    kh0[f] = *reinterpret_cast<const hfrag*>(kph + f * 16);
    kh1[f] = *reinterpret_cast<const hfrag*>(kph + SUB + f * 16);
  }
  svh0 = *reinterpret_cast<const bfrag*>(vph);
  svh1 = *reinterpret_cast<const bfrag*>(vph + SUB);
  vph += KSTEP;
  VSTAGE(0);
  f16v sA0, sA1, sB0, sB1;
#pragma unroll
  for (int r = 0; r < 16; ++r) { sA0[r] = 0.f; sA1[r] = 0.f; }
  __builtin_amdgcn_s_setprio(1);
#pragma unroll
  for (int f = 0; f < 4; ++f) {
    sA0 = MFMA32H(kh0[f], qh[f], sA0);
    sA1 = MFMA32H(kh1[f], qh[f], sA1);
  }
  __builtin_amdgcn_s_setprio(0);
  kph += KSTEP;
#pragma unroll
  for (int f = 0; f < 4; ++f) {
    kh0[f] = *reinterpret_cast<const hfrag*>(kph + f * 16);
    kh1[f] = *reinterpret_cast<const hfrag*>(kph + SUB + f * 16);
  }
  __syncthreads();

  f16v oA0, oA1;
#pragma unroll
  for (int r = 0; r < 16; ++r) { oA0[r] = 0.f; oA1[r] = 0.f; }
  float m2 = -1e30f, l_i = 0.f;  // running max in exp2 domain

#define ATTN_ITER(KT, SC0, SC1, SN0, SN1)                                      \
  do {                                                                         \
    const int kt_ = (KT);                                                      \
    const int cur_ = kt_ & 1;                                                  \
    /* 1: issue QK(kt+1) into SN pair (overlaps softmax below) */              \
    if (kt_ < 31) {                                                            \
      _Pragma("unroll") for (int r = 0; r < 16; ++r) { SN0[r] = 0.f; SN1[r] = 0.f; } \
      __builtin_amdgcn_s_setprio(1);                                           \
      _Pragma("unroll") for (int f = 0; f < 4; ++f) {                          \
        SN0 = MFMA32H(kh0[f], qh[f], SN0);                                     \
        SN1 = MFMA32H(kh1[f], qh[f], SN1);                                     \
      }                                                                        \
      __builtin_amdgcn_s_setprio(0);                                           \
    }                                                                          \
    /* 2: K(kt+2) loads */                                                     \
    if (kt_ < 30) {                                                            \
      kph += KSTEP;                                                            \
      _Pragma("unroll") for (int f = 0; f < 4; ++f) {                          \
        kh0[f] = *reinterpret_cast<const hfrag*>(kph + f * 16);                \
        kh1[f] = *reinterpret_cast<const hfrag*>(kph + SUB + f * 16);          \
      }                                                                        \
    }                                                                          \
    /* 3: softmax over both sub-tiles — max3 trees + exp2 domain */            \
    float t0 = max3f(SC0[0], SC0[1], SC0[2]);                                  \
    float t1 = max3f(SC0[3], SC0[4], SC0[5]);                                  \
    float t2 = max3f(SC0[6], SC0[7], SC0[8]);                                  \
    float t3 = max3f(SC0[9], SC0[10], SC0[11]);                                \
    float t4 = max3f(SC0[12], SC0[13], SC0[14]);                               \
    float t5 = max3f(SC1[0], SC1[1], SC1[2]);                                  \
    float t6 = max3f(SC1[3], SC1[4], SC1[5]);                                  \
    float t7 = max3f(SC1[6], SC1[7], SC1[8]);                                  \
    float t8 = max3f(SC1[9], SC1[10], SC1[11]);                                \
    float t9 = max3f(SC1[12], SC1[13], SC1[14]);                               \
    float u0 = max3f(t0, t1, SC0[15]);                                         \
    float u1 = max3f(t2, t3, t4);                                              \
    float u2 = max3f(t5, t6, SC1[15]);                                         \
    float u3 = max3f(t7, t8, t9);                                              \
    float mt = fmaxf(max3f(u0, u1, u2), u3);                                   \
    mt = fmaxf(mt, __shfl_xor(mt, 32));                                        \
    float mt2 = mt * C;                                                        \
    if (!__all(mt2 <= m2)) { /* defer-max: THR=0, corr=2^0=1 exact */          \
      float mn = fmaxf(m2, mt2);                                               \
      float corr = exp2_fast(m2 - mn);                                         \
      m2 = mn;                                                                 \
      l_i *= corr;                                                             \
      _Pragma("unroll") for (int r = 0; r < 16; ++r) {                         \
        oA0[r] *= corr; oA1[r] *= corr;                                        \
      }                                                                        \
    }                                                                          \
    float p0[16], p1[16];                                                      \
    _Pragma("unroll") for (int r = 0; r < 16; ++r) {                           \
      p0[r] = exp2_fast(fmaf(SC0[r], C, -m2));                                 \
      p1[r] = exp2_fast(fmaf(SC1[r], C, -m2));                                 \
    }                                                                          \
    float ra_ = ((p0[0] + p0[1]) + (p0[2] + p0[3])) +                          \
                ((p0[4] + p0[5]) + (p0[6] + p0[7]));                           \
    float rb_ = ((p0[8] + p0[9]) + (p0[10] + p0[11])) +                        \
                ((p0[12] + p0[13]) + (p0[14] + p0[15]));                       \
    float rc_ = ((p1[0] + p1[1]) + (p1[2] + p1[3])) +                          \
                ((p1[4] + p1[5]) + (p1[6] + p1[7]));                           \
    float rd_ = ((p1[8] + p1[9]) + (p1[10] + p1[11])) +                        \
                ((p1[12] + p1[13]) + (p1[14] + p1[15]));                       \
    float rs = (ra_ + rb_) + (rc_ + rd_);                                      \
    rs += __shfl_xor(rs, 32);                                                  \
    l_i += rs;                                                                 \
    /* 4: issue V(kt+1) loads (written to LDS at step 7) */                    \
    if (kt_ < 31) {                                                            \
      svh0 = *reinterpret_cast<const bfrag*>(vph);                             \
      svh1 = *reinterpret_cast<const bfrag*>(vph + SUB);                       \
      vph += KSTEP;                                                            \
    }                                                                          \
    /* 5: pack P (fp16, RTZ) + permlane32_swap frag build, both sub-tiles */   \
    unsigned pa_[8], pb_[8];                                                   \
    _Pragma("unroll") for (int i = 0; i < 8; ++i) {                            \
      pa_[i] = cvt_pkrtz_u(p0[2 * i], p0[2 * i + 1]);                          \
      pb_[i] = cvt_pkrtz_u(p1[2 * i], p1[2 * i + 1]);                          \
    }                                                                          \
    permswap(pa_[0], pa_[2]); permswap(pa_[1], pa_[3]);                        \
    permswap(pa_[4], pa_[6]); permswap(pa_[5], pa_[7]);                        \
    permswap(pb_[0], pb_[2]); permswap(pb_[1], pb_[3]);                        \
    permswap(pb_[4], pb_[6]); permswap(pb_[5], pb_[7]);                        \
    union U4 { unsigned u[4]; hfrag f; };                                      \
    U4 f0h, f1h, f2h, f3h;                                                     \
    f0h.u[0] = pa_[0]; f0h.u[1] = pa_[1]; f0h.u[2] = pa_[2]; f0h.u[3] = pa_[3];\
    f1h.u[0] = pa_[4]; f1h.u[1] = pa_[5]; f1h.u[2] = pa_[6]; f1h.u[3] = pa_[7];\
    f2h.u[0] = pb_[0]; f2h.u[1] = pb_[1]; f2h.u[2] = pb_[2]; f2h.u[3] = pb_[3];\
    f3h.u[0] = pb_[4]; f3h.u[1] = pb_[5]; f3h.u[2] = pb_[6]; f3h.u[3] = pb_[7];\
    /* 6: PV(kt): both sub-tiles from LDS[cur_], rho rows */                   \
    __builtin_amdgcn_s_setprio(1);                                             \
    _Pragma("unroll") for (int c = 0; c < 2; ++c) {                            \
      hfrag pF0 = c ? f1h.f : f0h.f;                                           \
      hfrag pF1 = c ? f3h.f : f2h.f;                                           \
      hfrag vA0 = *reinterpret_cast<const hfrag*>(&Vth[cur_][rA][c * 16 + hi * 8]);      \
      hfrag vA1 = *reinterpret_cast<const hfrag*>(&Vth[cur_][rA][32 + c * 16 + hi * 8]); \
      hfrag vB0 = *reinterpret_cast<const hfrag*>(&Vth[cur_][rB][c * 16 + hi * 8]);      \
      hfrag vB1 = *reinterpret_cast<const hfrag*>(&Vth[cur_][rB][32 + c * 16 + hi * 8]); \
      oA0 = MFMA32H(vA0, pF0, oA0);                                            \
      oA1 = MFMA32H(vB0, pF0, oA1);                                            \
      oA0 = MFMA32H(vA1, pF1, oA0);                                            \
      oA1 = MFMA32H(vB1, pF1, oA1);                                            \
    }                                                                          \
    __builtin_amdgcn_s_setprio(0);                                             \
    /* 7: write staged V(kt+1) (static element, rho rows), barrier */          \
    if (kt_ < 31) {                                                            \
      VSTAGE(cur_ ^ 1);                                                        \
      __syncthreads();                                                         \
    }                                                                          \
  } while (0)

  for (int kt = 0; kt < 32; kt += 2) {
    ATTN_ITER(kt, sA0, sA1, sB0, sB1);
    ATTN_ITER(kt + 1, sB0, sB1, sA0, sA1);
  }
#undef ATTN_ITER
#undef VSTAGE

  // ---- epilogue: normalize, store FP16 [B,S,H*Dh] ----
  float inv = 1.0f / l_i;
  const size_t orow = (bbase + q0 + q) * 1024 + hoff;
#pragma unroll
  for (int dblk = 0; dblk < 2; ++dblk) {
#pragma unroll
    for (int rg = 0; rg < 4; ++rg) {
      us4 o;
#pragma unroll
      for (int e = 0; e < 4; ++e) {
        float v = (dblk == 0 ? oA0[rg * 4 + e] : oA1[rg * 4 + e]) * inv;
        o[e] = f2h_bits(v);
      }
      *reinterpret_cast<us4*>(out16 + orow + dblk * 32 + rg * 8 + hi * 4) = o;
    }
  }
}

// ---------------------------------------------------------------------------
// Workspace layout (56.25 MiB used):
//   @ 0        : x_q fp16-codes (8 MiB)     @ 8 MiB : s_x (128 KiB)
//   @ 8.25 MiB : WTqkv fp16 (6 MiB)         @ 20.25 : WTout fp16 (2 MiB)
//   @ 24.25    : qkv fp16 single (24 MiB)   @ 48.25 : y16 fp16 (8 MiB)
// ---------------------------------------------------------------------------
extern "C" void kernel_launch(void* const* d_in, const int* in_sizes, int n_in,
                              void* d_out, int out_size, void* d_ws, size_t ws_size,
                              hipStream_t stream) {
  const float* x     = (const float*)d_in[0];
  const float* W_qkv = (const float*)d_in[1];
  const float* b_qkv = (const float*)d_in[2];
  const float* W_out = (const float*)d_in[3];
  const float* b_out = (const float*)d_in[4];
  float* y = (float*)d_out;

  char* ws = (char*)d_ws;
  const size_t MB = 1u << 20;
  unsigned short* x_q   = (unsigned short*)(ws);
  float*          s_x   = (float*)(ws + 8 * MB);
  unsigned short* wqh   = (unsigned short*)(ws + 8 * MB + 256 * 1024);
  unsigned short* woh   = (unsigned short*)(ws + 20 * MB + 256 * 1024);
  unsigned short* qkv   = (unsigned short*)(ws + 24 * MB + 256 * 1024);
  unsigned short* y16   = (unsigned short*)(ws + 48 * MB + 256 * 1024);

  // 1. quantize activations (fp16 codes + scales) and weights (fp16 dequant)
  quant_x<<<8192, 256, 0, stream>>>(x, x_q, s_x, 32768);
  quant_w_t<<<dim3(24, 16), 256, 0, stream>>>(W_qkv, wqh, 1024, 3072);
  quant_w_t<<<dim3(8, 16), 256, 0, stream>>>(W_out, woh, 1024, 1024);

  // 2. QKV projection (fp16 1-pass MFMA) -> single fp16 stream
  gemm_q<4, true><<<768, 256, 0, stream>>>(x_q, s_x, wqh, b_qkv,
                                           nullptr, qkv, 4096, 3072, 1024);

  // 3. KBLK=64 single-stream fp16 flash attention -> fp16 y16
  attn_mfma32<<<512, 256, 0, stream>>>(qkv, y16);

  // 4. quantize attention output (fp16 input; reuse x_q / s_x buffers)
  quant_xh<<<8192, 256, 0, stream>>>(y16, x_q, s_x, 32768);

  // 5. output projection (fp16 1-pass): 64x128 tiles -> 512 blocks
  gemm_q<2, false><<<512, 256, 0, stream>>>(x_q, s_x, woh, b_out,
                                            y, nullptr, 4096, 1024, 1024);
}

// Round 26
// 168.761 us; speedup vs baseline: 1.0240x; 1.0240x over previous
//
#include <hip/hip_runtime.h>
#include <cstdint>
#include <cstddef>

typedef __attribute__((ext_vector_type(8))) short bfrag;      // 8x16-bit (4 VGPR)
typedef __attribute__((ext_vector_type(8))) _Float16 hfrag;   // 8 f16 (4 VGPR)
typedef __attribute__((ext_vector_type(2))) __fp16 fp16x2;    // cvt_pkrtz result type
typedef __attribute__((ext_vector_type(4))) float f4;         // 16x16 MFMA C/D
typedef __attribute__((ext_vector_type(16))) float f16v;      // 32x32 MFMA C/D
typedef __attribute__((ext_vector_type(4))) unsigned short us4;

#define MFMA16H(a, b, c) __builtin_amdgcn_mfma_f32_16x16x32_f16(a, b, c, 0, 0, 0)
#define MFMA32H(a, b, c) __builtin_amdgcn_mfma_f32_32x32x16_f16(a, b, c, 0, 0, 0)

// ---------------------------------------------------------------------------
// fp16 / math helpers.
// ---------------------------------------------------------------------------
__device__ __forceinline__ unsigned cvt_pkrtz_u(float a, float b) {
  union { fp16x2 h; unsigned u; } c;
  c.h = __builtin_amdgcn_cvt_pkrtz(a, b);
  return c.u;
}
__device__ __forceinline__ unsigned short f2h_bits(float x) {  // RNE
  _Float16 h = (_Float16)x;
  union { _Float16 h; unsigned short u; } c;
  c.h = h;
  return c.u;
}
__device__ __forceinline__ float h2f(unsigned short u) {
  union { unsigned short u; _Float16 h; } c;
  c.u = u;
  return (float)c.h;
}
// One-instruction cross-half exchange: a' = [a_lo | b_lo], b' = [a_hi | b_hi].
__device__ __forceinline__ void permswap(unsigned& a, unsigned& b) {
  auto r = __builtin_amdgcn_permlane32_swap((int)a, (int)b, false, false);
  a = (unsigned)r[0];
  b = (unsigned)r[1];
}
// Async global->LDS, 16B per lane. Dest is wave-uniform base + lane*16.
__device__ __forceinline__ void gl16(const unsigned short* g, unsigned short* l) {
  __builtin_amdgcn_global_load_lds(
      (const __attribute__((address_space(1))) unsigned int*)g,
      (__attribute__((address_space(3))) unsigned int*)l, 16, 0, 0);
}
// 3-input max (single instruction, T17).
__device__ __forceinline__ float max3f(float a, float b, float c) {
  float r;
  asm("v_max3_f32 %0, %1, %2, %3" : "=v"(r) : "v"(a), "v"(b), "v"(c));
  return r;
}
// Raw v_exp_f32 (computes 2^x).
__device__ __forceinline__ float exp2_fast(float x) {
  float r;
  asm("v_exp_f32 %0, %1" : "=v"(r) : "v"(x));
  return r;
}

// ---------------------------------------------------------------------------
// Software-exact OCP e4m3fn rounding (RTNE via magic-add; matches ml_dtypes
// bit-exact incl. subnormal grid 2^-9 and the 448-saturation region).
// ---------------------------------------------------------------------------
__device__ __forceinline__ float qd_e4m3(float v) {
  float a = fabsf(v);
  unsigned u = __float_as_uint(a);
  int e = (int)(u >> 23) - 127;
  int k = e - 3;
  if (k < -9) k = -9;
  float big = __uint_as_float((unsigned)(k + 150) << 23);  // 2^(k+23)
  float r = (a + big) - big;
  return __builtin_copysignf(r, v);
}

// ---------------------------------------------------------------------------
// Activation quant (fp32 input): per 128-block, e4m3 codes as fp16 + scale.
// ---------------------------------------------------------------------------
__global__ __launch_bounds__(256) void quant_x(const float* __restrict__ src,
                                               unsigned short* __restrict__ q,
                                               float* __restrict__ s,
                                               int nblk) {
  int gid = blockIdx.x * 256 + threadIdx.x;
  int wid = gid >> 6;
  int lane = gid & 63;
  if (wid >= nblk) return;
  size_t off = (size_t)wid * 128 + lane * 2;
  float2 xv = *reinterpret_cast<const float2*>(src + off);
  float m = fmaxf(fabsf(xv.x), fabsf(xv.y));
#pragma unroll
  for (int d = 32; d > 0; d >>= 1) m = fmaxf(m, __shfl_xor(m, d));
  float scale = fmaxf(m / 448.0f, 1e-12f);
  unsigned short q0 = f2h_bits(qd_e4m3(xv.x / scale));  // exact: e4m3 ⊂ fp16
  unsigned short q1 = f2h_bits(qd_e4m3(xv.y / scale));
  *reinterpret_cast<unsigned*>(q + off) = (unsigned)q0 | ((unsigned)q1 << 16);
  if (lane == 0) s[wid] = scale;
}

// ---------------------------------------------------------------------------
// Activation quant (fp16 input): same math, reads half the bytes.
// ---------------------------------------------------------------------------
__global__ __launch_bounds__(256) void quant_xh(const unsigned short* __restrict__ src,
                                                unsigned short* __restrict__ q,
                                                float* __restrict__ s,
                                                int nblk) {
  int gid = blockIdx.x * 256 + threadIdx.x;
  int wid = gid >> 6;
  int lane = gid & 63;
  if (wid >= nblk) return;
  size_t off = (size_t)wid * 128 + lane * 2;
  unsigned hv = *reinterpret_cast<const unsigned*>(src + off);
  float x0 = h2f((unsigned short)(hv & 0xffffu));
  float x1 = h2f((unsigned short)(hv >> 16));
  float m = fmaxf(fabsf(x0), fabsf(x1));
#pragma unroll
  for (int d = 32; d > 0; d >>= 1) m = fmaxf(m, __shfl_xor(m, d));
  float scale = fmaxf(m / 448.0f, 1e-12f);
  unsigned short q0 = f2h_bits(qd_e4m3(x0 / scale));
  unsigned short q1 = f2h_bits(qd_e4m3(x1 / scale));
  *reinterpret_cast<unsigned*>(q + off) = (unsigned)q0 | ((unsigned)q1 << 16);
  if (lane == 0) s[wid] = scale;
}

// ---------------------------------------------------------------------------
// Weight quant + dequant -> FP16 (RNE, rel err <= 2^-12) + TRANSPOSE.
// ---------------------------------------------------------------------------
__global__ __launch_bounds__(256) void quant_w_t(const float* __restrict__ W,
                                                 unsigned short* __restrict__ WT,
                                                 int K, int N) {
  __shared__ __align__(16) unsigned short Ht[128][72];
  const int tid = threadIdx.x;
  const int w = tid >> 6, l = tid & 63;
  const int k0 = blockIdx.y * 64, n0 = blockIdx.x * 128;
#pragma unroll 4
  for (int i = 0; i < 16; ++i) {
    int kl = w * 16 + i;
    float2 xv = *reinterpret_cast<const float2*>(&W[(size_t)(k0 + kl) * N + n0 + l * 2]);
    float m = fmaxf(fabsf(xv.x), fabsf(xv.y));
#pragma unroll
    for (int d = 32; d > 0; d >>= 1) m = fmaxf(m, __shfl_xor(m, d));
    float scale = fmaxf(m / 448.0f, 1e-12f);
    Ht[l * 2][kl]     = f2h_bits(qd_e4m3(xv.x / scale) * scale);
    Ht[l * 2 + 1][kl] = f2h_bits(qd_e4m3(xv.y / scale) * scale);
  }
  __syncthreads();
  const int n = tid & 127, hs = tid >> 7;   // thread -> (n-row, k-half)
  unsigned short* dst = WT + (size_t)(n0 + n) * K + k0 + hs * 32;
#pragma unroll
  for (int j = 0; j < 4; ++j)
    *reinterpret_cast<bfrag*>(dst + j * 8) =
        *reinterpret_cast<const bfrag*>(&Ht[n][hs * 32 + j * 8]);
}

// ---------------------------------------------------------------------------
// Quantization-aware MFMA GEMM, FP16 1-PASS.
// ---------------------------------------------------------------------------
template <int MF, bool SPLIT>
__global__ __launch_bounds__(256, 2) void gemm_q(const unsigned short* __restrict__ Aq,
                                                 const float* __restrict__ As,
                                                 const unsigned short* __restrict__ WT,
                                                 const float* __restrict__ bias,
                                                 float* __restrict__ Cf,
                                                 unsigned short* __restrict__ C16,
                                                 int M, int N, int K) {
  constexpr int MT = MF * 32;
  __shared__ __align__(16) unsigned short Al[MT][64];
  __shared__ __align__(16) unsigned short Bh[128][64];
  __shared__ float Ss[MT][8];
  const int tid = threadIdx.x;
  const int w = tid >> 6, l = tid & 63;
  const int lr = l & 15, lg = l >> 4;
  const int nbx = N >> 7;
  const int nwg = nbx * (M / MT);
  const int q8 = nwg >> 3;
  const int swz = ((int)blockIdx.x & 7) * q8 + ((int)blockIdx.x >> 3);
  const int row0 = (swz / nbx) * MT, col0 = (swz % nbx) << 7;
  const int wr = (w >> 1) * (MT / 2), wc = (w & 1) * 64;
  const int xsw = (lr & 7) * 8;        // read-side XOR (short units)

  if (MF == 4) {
    int r = tid >> 1, c0 = (tid & 1) * 4;
    *reinterpret_cast<float4*>(&Ss[r][c0]) =
        *reinterpret_cast<const float4*>(&As[(size_t)(row0 + r) * 8 + c0]);
  } else {
    int r = tid >> 2, c0 = (tid & 3) * 2;
    *reinterpret_cast<float2*>(&Ss[r][c0]) =
        *reinterpret_cast<const float2*>(&As[(size_t)(row0 + r) * 8 + c0]);
  }

  f4 acc[MF][4], seg[MF][4];
#pragma unroll
  for (int i = 0; i < MF; ++i)
#pragma unroll
    for (int j = 0; j < 4; ++j)
#pragma unroll
      for (int c = 0; c < 4; ++c) {
        acc[i][j][c] = 0.f;
        seg[i][j][c] = 0.f;
      }

  const int lrow = l >> 3;             // 0..7
  const int jch = (l & 7) ^ lrow;      // inverse-swizzled source chunk
  const unsigned short* pA = Aq + (size_t)(row0 + w * (MT / 4) + lrow) * K + jch * 8;
  const unsigned short* pH = WT + (size_t)(col0 + w * 32 + lrow) * K + jch * 8;
  unsigned short* dA = &Al[0][0] + w * (MT / 4) * 64;
  unsigned short* dH = &Bh[0][0] + w * 2048;

  const int niter = K >> 6;
  for (int it = 0; it < niter; ++it) {
    const int k0 = it << 6;
    __syncthreads();
#pragma unroll
    for (int ii = 0; ii < MF; ++ii)
      gl16(pA + (size_t)ii * 8 * K + k0, dA + ii * 512);
#pragma unroll
    for (int ii = 0; ii < 4; ++ii)
      gl16(pH + (size_t)ii * 8 * K + k0, dH + ii * 512);
    __syncthreads();

#pragma unroll
    for (int ks = 0; ks < 2; ++ks) {
      hfrag af[MF];
#pragma unroll
      for (int mf = 0; mf < MF; ++mf)
        af[mf] = *reinterpret_cast<const hfrag*>(
            &Al[0][0] + (wr + mf * 16 + lr) * 64 + ((ks * 32 + lg * 8) ^ xsw));
#pragma unroll
      for (int nf = 0; nf < 4; ++nf) {
        hfrag bh = *reinterpret_cast<const hfrag*>(
            &Bh[0][0] + (wc + nf * 16 + lr) * 64 + ((ks * 32 + lg * 8) ^ xsw));
#pragma unroll
        for (int mf = 0; mf < MF; ++mf)
          seg[mf][nf] = MFMA16H(af[mf], bh, seg[mf][nf]);
      }
    }

    if (it & 1) {
      const int kb = it >> 1;
#pragma unroll
      for (int mf = 0; mf < MF; ++mf) {
        float sv[4];
#pragma unroll
        for (int r = 0; r < 4; ++r) sv[r] = Ss[wr + mf * 16 + lg * 4 + r][kb];
#pragma unroll
        for (int nf = 0; nf < 4; ++nf)
#pragma unroll
          for (int r = 0; r < 4; ++r) {
            acc[mf][nf][r] += sv[r] * seg[mf][nf][r];
            seg[mf][nf][r] = 0.f;
          }
      }
    }
  }

#pragma unroll
  for (int mf = 0; mf < MF; ++mf) {
#pragma unroll
    for (int r = 0; r < 4; ++r) {
      const int m = row0 + wr + mf * 16 + lg * 4 + r;
#pragma unroll
      for (int nf = 0; nf < 4; ++nf) {
        const int col = col0 + wc + nf * 16 + lr;
        float o = acc[mf][nf][r] + bias[col];
        if (SPLIT) {
          C16[(size_t)m * N + col] = f2h_bits(o);  // single fp16 stream
        } else {
          Cf[(size_t)m * N + col] = o;
        }
      }
    }
  }
}

// ---------------------------------------------------------------------------
// Single-stream fp16 1-pass flash attention (round-22 structure) with fp16
// output epilogue (round 24) — the measured best configuration.
// ---------------------------------------------------------------------------
__global__ __launch_bounds__(256, 2) void attn_mfma32(const unsigned short* __restrict__ qkv,
                                                      unsigned short* __restrict__ out16) {
  __shared__ __align__(16) unsigned short Vth[2][64][40];  // V^T: [buf][rho(d)][kpos]
  const int tid = threadIdx.x;
  const int w = tid >> 6, l = tid & 63;
  const int q = l & 31;
  const int hi = l >> 5;
  // XCD-aware decode: XCD k owns bh in {4k..4k+3} (2 MB KV -> L2-resident)
  const int lin = (int)blockIdx.x;
  const int xcd = lin & 7, j = lin >> 3;
  const int bh = 4 * xcd + (j >> 4);
  const int qt = j & 15;
  const int q0 = qt * 128 + w * 32;
  const int b = bh >> 4, h = bh & 15;
  const size_t bbase = (size_t)b * 2048;
  const size_t hoff = (size_t)h * 64;
  const float C = 0.18033688011112042f;  // 0.125 * log2(e)

  const int rA = (q & 24) | ((q + (q >> 3)) & 7);              // d = q
  const int rB = 32 + ((q & 24) | ((q + 4 + (q >> 3)) & 7));   // d = 32+q

  hfrag qh[4];
  {
    const size_t qrow = (bbase + q0 + q) * 3072 + hoff + hi * 8;
#pragma unroll
    for (int f = 0; f < 4; ++f)
      qh[f] = *reinterpret_cast<const hfrag*>(qkv + qrow + f * 16);
  }

  const int skp = tid >> 3;   // 0..31 (kpos)
  const int sc = tid & 7;     // 0..7  (d-chunk of 8)

  const unsigned short* kph = qkv + (bbase + q) * 3072 + 1024 + hoff + hi * 8;
  const unsigned short* vph = qkv + (bbase + skp) * 3072 + 2048 + hoff + sc * 8;
  const size_t KSTEP = (size_t)32 * 3072;

  hfrag kh[4];
  bfrag svh;

  // ---- prologue: K(0), V(0)->LDS0, QK(0)->sA, K(1) ----
#pragma unroll
  for (int f = 0; f < 4; ++f)
    kh[f] = *reinterpret_cast<const hfrag*>(kph + f * 16);
  svh = *reinterpret_cast<const bfrag*>(vph);
  vph += KSTEP;
#pragma unroll
  for (int j2 = 0; j2 < 8; ++j2) {  // static element j2 -> row rho(sc*8+j2)
    int row = sc * 8 + ((j2 + sc) & 7);
    Vth[0][row][skp] = (unsigned short)svh[j2];
  }
  f16v sA, sB;
#pragma unroll
  for (int r = 0; r < 16; ++r) sA[r] = 0.f;
  __builtin_amdgcn_s_setprio(1);
#pragma unroll
  for (int f = 0; f < 4; ++f) sA = MFMA32H(kh[f], qh[f], sA);
  __builtin_amdgcn_s_setprio(0);
  kph += KSTEP;
#pragma unroll
  for (int f = 0; f < 4; ++f)
    kh[f] = *reinterpret_cast<const hfrag*>(kph + f * 16);
  __syncthreads();

  f16v oA0, oA1;
#pragma unroll
  for (int r = 0; r < 16; ++r) { oA0[r] = 0.f; oA1[r] = 0.f; }
  float m2 = -1e30f, l_i = 0.f;  // running max in exp2 domain

#define ATTN_ITER(KT, SCUR, SNXT)                                              \
  do {                                                                         \
    const int kt_ = (KT);                                                      \
    const int cur_ = kt_ & 1;                                                  \
    /* 1: issue QK(kt+1) into SNXT (1-pass f16; overlaps softmax below) */     \
    if (kt_ < 63) {                                                            \
      _Pragma("unroll") for (int r = 0; r < 16; ++r) SNXT[r] = 0.f;            \
      __builtin_amdgcn_s_setprio(1);                                           \
      _Pragma("unroll") for (int f = 0; f < 4; ++f)                            \
          SNXT = MFMA32H(kh[f], qh[f], SNXT);                                  \
      __builtin_amdgcn_s_setprio(0);                                           \
    }                                                                          \
    /* 2: K(kt+2) loads */                                                     \
    if (kt_ < 62) {                                                            \
      kph += KSTEP;                                                            \
      _Pragma("unroll") for (int f = 0; f < 4; ++f)                            \
          kh[f] = *reinterpret_cast<const hfrag*>(kph + f * 16);               \
    }                                                                          \
    /* 3: softmax on SCUR — max3 tree + exp2 domain */                         \
    float t0 = max3f(SCUR[0], SCUR[1], SCUR[2]);                               \
    float t1 = max3f(SCUR[3], SCUR[4], SCUR[5]);                               \
    float t2 = max3f(SCUR[6], SCUR[7], SCUR[8]);                               \
    float t3 = max3f(SCUR[9], SCUR[10], SCUR[11]);                             \
    float t4 = max3f(SCUR[12], SCUR[13], SCUR[14]);                            \
    float u0 = max3f(t0, t1, SCUR[15]);                                        \
    float u1 = max3f(t2, t3, t4);                                              \
    float mt = fmaxf(u0, u1);                                                  \
    mt = fmaxf(mt, __shfl_xor(mt, 32));                                        \
    float mt2 = mt * C;                                                        \
    if (!__all(mt2 <= m2)) { /* defer-max: THR=0, corr=2^0=1 exact */          \
      float mn = fmaxf(m2, mt2);                                               \
      float corr = exp2_fast(m2 - mn);                                         \
      m2 = mn;                                                                 \
      l_i *= corr;                                                             \
      _Pragma("unroll") for (int r = 0; r < 16; ++r) {                         \
        oA0[r] *= corr; oA1[r] *= corr;                                        \
      }                                                                        \
    }                                                                          \
    float p[16];                                                               \
    _Pragma("unroll") for (int r = 0; r < 16; ++r)                             \
        p[r] = exp2_fast(fmaf(SCUR[r], C, -m2));                               \
    float r0_ = (p[0] + p[1]) + (p[2] + p[3]);                                 \
    float r1_ = (p[4] + p[5]) + (p[6] + p[7]);                                 \
    float r2_ = (p[8] + p[9]) + (p[10] + p[11]);                               \
    float r3_ = (p[12] + p[13]) + (p[14] + p[15]);                             \
    float rs = (r0_ + r1_) + (r2_ + r3_);                                      \
    rs += __shfl_xor(rs, 32);                                                  \
    l_i += rs;                                                                 \
    /* 4: issue V(kt+1) load (written to LDS at step 7) */                     \
    if (kt_ < 63) {                                                            \
      svh = *reinterpret_cast<const bfrag*>(vph);                              \
      vph += KSTEP;                                                            \
    }                                                                          \
    /* 5: pack P (fp16, RTZ) + permlane32_swap frag build */                   \
    unsigned ph_[8];                                                           \
    _Pragma("unroll") for (int i = 0; i < 8; ++i)                              \
        ph_[i] = cvt_pkrtz_u(p[2 * i], p[2 * i + 1]);                          \
    permswap(ph_[0], ph_[2]); permswap(ph_[1], ph_[3]);                        \
    permswap(ph_[4], ph_[6]); permswap(ph_[5], ph_[7]);                        \
    union U4 { unsigned u[4]; hfrag f; };                                      \
    U4 f0h, f1h;                                                               \
    f0h.u[0] = ph_[0]; f0h.u[1] = ph_[1]; f0h.u[2] = ph_[2]; f0h.u[3] = ph_[3];\
    f1h.u[0] = ph_[4]; f1h.u[1] = ph_[5]; f1h.u[2] = ph_[6]; f1h.u[3] = ph_[7];\
    /* 6: PV(kt) from LDS[cur_], rho rows; 1-pass Vh·Ph */                     \
    __builtin_amdgcn_s_setprio(1);                                             \
    _Pragma("unroll") for (int c = 0; c < 2; ++c) {                            \
      hfrag pF = c ? f1h.f : f0h.f;                                            \
      hfrag vh0 = *reinterpret_cast<const hfrag*>(&Vth[cur_][rA][c * 16 + hi * 8]); \
      hfrag vh1 = *reinterpret_cast<const hfrag*>(&Vth[cur_][rB][c * 16 + hi * 8]); \
      oA0 = MFMA32H(vh0, pF, oA0);                                             \
      oA1 = MFMA32H(vh1, pF, oA1);                                             \
    }                                                                          \
    __builtin_amdgcn_s_setprio(0);                                             \
    /* 7: write staged V(kt+1) (static element, rho rows), barrier */          \
    if (kt_ < 63) {                                                            \
      _Pragma("unroll") for (int j2 = 0; j2 < 8; ++j2) {                       \
        int row = sc * 8 + ((j2 + sc) & 7);                                    \
        Vth[cur_ ^ 1][row][skp] = (unsigned short)svh[j2];                     \
      }                                                                        \
      __syncthreads();                                                         \
    }                                                                          \
  } while (0)

  for (int kt = 0; kt < 64; kt += 2) {
    ATTN_ITER(kt, sA, sB);
    ATTN_ITER(kt + 1, sB, sA);
  }
#undef ATTN_ITER

  // ---- epilogue: normalize, store FP16 [B,S,H*Dh] ----
  float inv = 1.0f / l_i;
  const size_t orow = (bbase + q0 + q) * 1024 + hoff;
#pragma unroll
  for (int dblk = 0; dblk < 2; ++dblk) {
#pragma unroll
    for (int rg = 0; rg < 4; ++rg) {
      us4 o;
#pragma unroll
      for (int e = 0; e < 4; ++e) {
        float v = (dblk == 0 ? oA0[rg * 4 + e] : oA1[rg * 4 + e]) * inv;
        o[e] = f2h_bits(v);
      }
      *reinterpret_cast<us4*>(out16 + orow + dblk * 32 + rg * 8 + hi * 4) = o;
    }
  }
}

// ---------------------------------------------------------------------------
// Workspace layout (56.25 MiB used):
//   @ 0        : x_q fp16-codes (8 MiB)     @ 8 MiB : s_x (128 KiB)
//   @ 8.25 MiB : WTqkv fp16 (6 MiB)         @ 20.25 : WTout fp16 (2 MiB)
//   @ 24.25    : qkv fp16 single (24 MiB)   @ 48.25 : y16 fp16 (8 MiB)
// ---------------------------------------------------------------------------
extern "C" void kernel_launch(void* const* d_in, const int* in_sizes, int n_in,
                              void* d_out, int out_size, void* d_ws, size_t ws_size,
                              hipStream_t stream) {
  const float* x     = (const float*)d_in[0];
  const float* W_qkv = (const float*)d_in[1];
  const float* b_qkv = (const float*)d_in[2];
  const float* W_out = (const float*)d_in[3];
  const float* b_out = (const float*)d_in[4];
  float* y = (float*)d_out;

  char* ws = (char*)d_ws;
  const size_t MB = 1u << 20;
  unsigned short* x_q   = (unsigned short*)(ws);
  float*          s_x   = (float*)(ws + 8 * MB);
  unsigned short* wqh   = (unsigned short*)(ws + 8 * MB + 256 * 1024);
  unsigned short* woh   = (unsigned short*)(ws + 20 * MB + 256 * 1024);
  unsigned short* qkv   = (unsigned short*)(ws + 24 * MB + 256 * 1024);
  unsigned short* y16   = (unsigned short*)(ws + 48 * MB + 256 * 1024);

  // 1. quantize activations (fp16 codes + scales) and weights (fp16 dequant)
  quant_x<<<8192, 256, 0, stream>>>(x, x_q, s_x, 32768);
  quant_w_t<<<dim3(24, 16), 256, 0, stream>>>(W_qkv, wqh, 1024, 3072);
  quant_w_t<<<dim3(8, 16), 256, 0, stream>>>(W_out, woh, 1024, 1024);

  // 2. QKV projection (fp16 1-pass MFMA) -> single fp16 stream
  gemm_q<4, true><<<768, 256, 0, stream>>>(x_q, s_x, wqh, b_qkv,
                                           nullptr, qkv, 4096, 3072, 1024);

  // 3. single-stream fp16 1-pass flash attention -> fp16 y16
  attn_mfma32<<<512, 256, 0, stream>>>(qkv, y16);

  // 4. quantize attention output (fp16 input; reuse x_q / s_x buffers)
  quant_xh<<<8192, 256, 0, stream>>>(y16, x_q, s_x, 32768);

  // 5. output projection (fp16 1-pass): 64x128 tiles -> 512 blocks
  gemm_q<2, false><<<512, 256, 0, stream>>>(x_q, s_x, woh, b_out,
                                            y, nullptr, 4096, 1024, 1024);
}